// Round 22
// baseline (1487.152 us; speedup 1.0000x reference)
//
#include <hip/hip_runtime.h>
#include <math.h>

// ---------------------------------------------------------------------------
// MultiScaleRetriever round 22: scores kernel -> 256x256 block / 8 waves /
// wave tile 128x64. Per K-64: 24 ds_read_b128 (288cy) vs 64 MFMA (320cy) ->
// MFMA-bound (R19/R21 showed 128^2's 16:32 ratio was LDS-read-bound at
// ~550us regardless of FETCH). Conflict-free 128B-row (row&7)<<4 layout
// (R19-vetted), single-buffer 2-barrier BK=64, 1 dispatch, XCD swizzle.
// Everything else byte-identical to passing R21.
// ---------------------------------------------------------------------------

static inline size_t align256(size_t x){ return (x + 255) & ~size_t(255); }

typedef short bf16x8 __attribute__((ext_vector_type(8)));
typedef float f32x4  __attribute__((ext_vector_type(4)));

#define GLOAD_LDS16(gp, lp) \
  __builtin_amdgcn_global_load_lds((const __attribute__((address_space(1))) unsigned int*)(gp), \
                                   (__attribute__((address_space(3))) unsigned int*)(lp), 16, 0, 0)

__device__ inline unsigned short f2bf(float f){
  unsigned int u = __float_as_uint(f);
  u += 0x7fffu + ((u >> 16) & 1u);
  return (unsigned short)(u >> 16);
}
__device__ inline float bf2f(unsigned int h16){
  return __uint_as_float(h16 << 16);
}

// ---------- fused: row 1/max(||x||,eps) + bf16 convert (optional row scale) ----------
template<bool SCALE_OUT>
__global__ __launch_bounds__(256) void rnorm_convert_kernel(
    const float* __restrict__ X, float* __restrict__ rn,
    unsigned short* __restrict__ out, int rows, int D)
{
  int wv = threadIdx.x >> 6, lane = threadIdx.x & 63;
  int r = blockIdx.x * 4 + wv;
  if (r >= rows) return;
  const float4* xr = (const float4*)(X + (size_t)r * D);
  int nv = D >> 2;
  float ss = 0.f;
  for (int i = lane; i < nv; i += 64){
    float4 v = xr[i];
    ss = fmaf(v.x,v.x, fmaf(v.y,v.y, fmaf(v.z,v.z, fmaf(v.w,v.w, ss))));
  }
  #pragma unroll
  for (int off = 32; off; off >>= 1) ss += __shfl_xor(ss, off);
  float rinv = 1.f / fmaxf(sqrtf(ss), 1e-12f);
  if (lane == 0) rn[r] = rinv;
  const float sc = SCALE_OUT ? rinv : 1.f;
  unsigned short* orow = out + (size_t)r * D;
  for (int i = lane; i < (D >> 3); i += 64){
    float4 v0 = xr[i*2], v1 = xr[i*2+1];
    v0.x*=sc; v0.y*=sc; v0.z*=sc; v0.w*=sc;
    v1.x*=sc; v1.y*=sc; v1.z*=sc; v1.w*=sc;
    uint4 w;
    w.x = (unsigned)f2bf(v0.x) | ((unsigned)f2bf(v0.y) << 16);
    w.y = (unsigned)f2bf(v0.z) | ((unsigned)f2bf(v0.w) << 16);
    w.z = (unsigned)f2bf(v1.x) | ((unsigned)f2bf(v1.y) << 16);
    w.w = (unsigned)f2bf(v1.z) | ((unsigned)f2bf(v1.w) << 16);
    *(uint4*)(orow + i*8) = w;
  }
}

// ---------- fp32 NT GEMM (proj/unify) ----------
template<int RM, int RN, bool ACCUM>
__global__ __launch_bounds__(256) void gemm_nt_kernel(
    const float* __restrict__ A, const float* __restrict__ B,
    const float* __restrict__ bias, const float* __restrict__ bscale,
    float* __restrict__ C, int M, int Nn, int K, int Brows, int ldc)
{
  __shared__ float As[16][RM*64 + 4];
  __shared__ float Bs[16][RN*64 + 4];
  const int t  = threadIdx.x;
  const int tm = t >> 4, tn = t & 15;
  const int m0 = blockIdx.y * (RM*64), n0 = blockIdx.x * (RN*64);

  float acc[RM][RN][4][4];
  #pragma unroll
  for (int r=0;r<RM;++r)
    #pragma unroll
    for (int c=0;c<RN;++c)
      #pragma unroll
      for (int i=0;i<4;++i)
        #pragma unroll
        for (int j=0;j<4;++j) acc[r][c][i][j]=0.f;

  for (int kp = 0; kp < K; kp += 16){
    #pragma unroll
    for (int l = 0; l < RM; ++l){
      int li = t + l*256;
      int row = li >> 2, kq = (li & 3) << 2;
      float4 v = *(const float4*)(A + (size_t)(m0+row)*K + kp + kq);
      As[kq+0][row]=v.x; As[kq+1][row]=v.y; As[kq+2][row]=v.z; As[kq+3][row]=v.w;
    }
    #pragma unroll
    for (int l = 0; l < RN; ++l){
      int li = t + l*256;
      int row = li >> 2, kq = (li & 3) << 2;
      int gn = n0 + row;
      float4 v = make_float4(0.f,0.f,0.f,0.f);
      float sc = 1.f;
      if (gn < Brows){
        v = *(const float4*)(B + (size_t)gn*K + kp + kq);
        if (bscale) sc = bscale[gn];
      }
      Bs[kq+0][row]=v.x*sc; Bs[kq+1][row]=v.y*sc; Bs[kq+2][row]=v.z*sc; Bs[kq+3][row]=v.w*sc;
    }
    __syncthreads();
    #pragma unroll
    for (int kk = 0; kk < 16; ++kk){
      float av[RM][4], bv[RN][4];
      #pragma unroll
      for (int r=0;r<RM;++r){
        float4 a = *(const float4*)&As[kk][r*64 + tm*4];
        av[r][0]=a.x; av[r][1]=a.y; av[r][2]=a.z; av[r][3]=a.w;
      }
      #pragma unroll
      for (int c=0;c<RN;++c){
        float4 b = *(const float4*)&Bs[kk][c*64 + tn*4];
        bv[c][0]=b.x; bv[c][1]=b.y; bv[c][2]=b.z; bv[c][3]=b.w;
      }
      #pragma unroll
      for (int r=0;r<RM;++r)
        #pragma unroll
        for (int c=0;c<RN;++c)
          #pragma unroll
          for (int i=0;i<4;++i)
            #pragma unroll
            for (int j=0;j<4;++j)
              acc[r][c][i][j] = fmaf(av[r][i], bv[c][j], acc[r][c][i][j]);
    }
    __syncthreads();
  }

  #pragma unroll
  for (int r=0;r<RM;++r){
    #pragma unroll
    for (int i=0;i<4;++i){
      int gm = m0 + r*64 + tm*4 + i;
      #pragma unroll
      for (int c=0;c<RN;++c){
        int gn = n0 + c*64 + tn*4;
        if (gn >= Nn) continue;
        float* cp = C + (size_t)gm*ldc + gn;
        float o0=acc[r][c][i][0], o1=acc[r][c][i][1], o2=acc[r][c][i][2], o3=acc[r][c][i][3];
        if (gn + 3 < Nn){
          float4 o = make_float4(o0,o1,o2,o3);
          if (bias){ float4 bb = *(const float4*)&bias[gn]; o.x+=bb.x; o.y+=bb.y; o.z+=bb.z; o.w+=bb.w; }
          if (ACCUM){ float4 cc = *(const float4*)cp; o.x+=cc.x; o.y+=cc.y; o.z+=cc.z; o.w+=cc.w; }
          *(float4*)cp = o;
        } else {
          float ov[4] = {o0,o1,o2,o3};
          for (int j=0;j<4;++j){
            if (gn + j < Nn){
              float o = ov[j];
              if (bias)  o += bias[gn+j];
              if (ACCUM) o += cp[j];
              cp[j] = o;
            }
          }
        }
      }
    }
  }
}

// ---------- scores GEMM v11: 256x256, 8 waves, wave tile 128x64, BK=64 ----------
// Single-buffer 2-barrier, 128B rows, (row&7)<<4 involution on gload source
// and ds_read. Per K-64/wave: 24 ds_read_b128, 64 MFMA -> MFMA-bound.
// 1D grid + bijective XCD swizzle, M-tile fastest (8 M-tiles per N-column).
__global__ __launch_bounds__(512, 2) void scores_mfma_kernel(
    const unsigned short* __restrict__ Abf, const unsigned short* __restrict__ Bbf,
    unsigned short* __restrict__ C, int M, int Nn, int K, int ldc)
{
  __shared__ __align__(16) unsigned char smem[65536];   // A:[0,32K) B:[32K,64K)

  const int t = threadIdx.x;
  const int lane = t & 63, wid = t >> 6;
  const int wm = wid >> 2, wn = wid & 3;       // 2 x 4 wave grid
  const int l15 = lane & 15, l4 = lane >> 4;

  // bijective XCD swizzle (m204)
  const int nwg = gridDim.x;
  const int q = nwg >> 3, r = nwg & 7;
  const int xcd = blockIdx.x & 7, idx = blockIdx.x >> 3;
  const int logical = (xcd < r ? xcd*(q+1) : r*(q+1) + (xcd-r)*q) + idx;
  const int mtiles = M >> 8;                   // M/256
  const int m0 = (logical % mtiles) * 256;
  const int n0 = (logical / mtiles) * 256;

  f32x4 acc[8][4];
  #pragma unroll
  for (int i=0;i<8;++i)
    #pragma unroll
    for (int j=0;j<4;++j) acc[i][j] = (f32x4)0.f;

  // staging: slot = t + i*512 (i=0..3); row = slot>>3 (0..255 over passes),
  // sb = (slot&7)*16. Wave-uniform dest base: wid*1024 + i*8192.
  const int srow = t >> 3;          // pass i adds 64
  const int sb   = (t & 7) * 16;
  const int ldsb = wid * 1024;

  for (int kp = 0; kp < K; kp += 64){
    #pragma unroll
    for (int i = 0; i < 4; ++i){
      int row = srow + i*64;
      int src = sb ^ ((row & 7) << 4);
      const unsigned char* ga = (const unsigned char*)Abf
          + ((size_t)(m0+row)*K + kp)*2 + src;
      GLOAD_LDS16(ga, smem + i*8192 + ldsb);
      int gn = n0 + row; if (gn >= Nn) gn = Nn - 1;   // clamp: junk cols never read
      const unsigned char* gb = (const unsigned char*)Bbf
          + ((size_t)gn*K + kp)*2 + src;
      GLOAD_LDS16(gb, smem + 32768 + i*8192 + ldsb);
    }
    __syncthreads();

    const unsigned char* As_ = smem;
    const unsigned char* Bs_ = smem + 32768;
    bf16x8 B0[4], B1[4];
    #pragma unroll
    for (int fn = 0; fn < 4; ++fn){
      int br = wn*64 + fn*16 + l15;
      int xr = (br & 7) << 4;
      const unsigned char* bp = Bs_ + br*128;
      B0[fn] = *(const bf16x8*)(bp + (( l4*16      ) ^ xr));
      B1[fn] = *(const bf16x8*)(bp + ((64 + l4*16 ) ^ xr));
    }
    #pragma unroll
    for (int fm = 0; fm < 8; ++fm){
      int ar = wm*128 + fm*16 + l15;
      int xr = (ar & 7) << 4;
      const unsigned char* ap = As_ + ar*128;
      bf16x8 A0 = *(const bf16x8*)(ap + (( l4*16      ) ^ xr));
      bf16x8 A1 = *(const bf16x8*)(ap + ((64 + l4*16 ) ^ xr));
      #pragma unroll
      for (int fn = 0; fn < 4; ++fn){
        acc[fm][fn] = __builtin_amdgcn_mfma_f32_16x16x32_bf16(A0, B0[fn], acc[fm][fn], 0,0,0);
        acc[fm][fn] = __builtin_amdgcn_mfma_f32_16x16x32_bf16(A1, B1[fn], acc[fm][fn], 0,0,0);
      }
    }
    __syncthreads();
  }

  // store bf16 scores: C/D layout col=lane&15, row=(lane>>4)*4+reg
  #pragma unroll
  for (int fm = 0; fm < 8; ++fm){
    int row = m0 + wm*128 + fm*16 + l4*4;
    #pragma unroll
    for (int fn = 0; fn < 4; ++fn){
      int col = n0 + wn*64 + fn*16 + l15;
      if (col < Nn){
        unsigned short* cp = C + (size_t)row*ldc + col;
        #pragma unroll
        for (int r2 = 0; r2 < 4; ++r2) cp[(size_t)r2*ldc] = f2bf(acc[fm][fn][r2]);
      }
    }
  }
}

// ---------- chunk filter v3: bf16 scores in, f32 LDS cache, ILP max ----------
__global__ __launch_bounds__(256) void chunk_filter_kernel(
    const unsigned short* __restrict__ scores, int ldc, int colbase, int Nwindow,
    int NC, float* __restrict__ cand_s, int* __restrict__ cand_i,
    int chunk0, int nchunks_total, int cap, float eps)
{
  extern __shared__ float lds[];          // NC floats
  __shared__ float sv[256];
  __shared__ float tau_s;
  __shared__ int cnt;
  const int row = blockIdx.x, t = threadIdx.x;
  const int lc = blockIdx.y;
  const int col0l = lc * NC;
  int ncols = Nwindow - col0l; if (ncols > NC) ncols = NC;
  const int gchunk = chunk0 + lc;
  const unsigned short* sr = scores + (size_t)row * ldc + col0l;

  float m0 = -INFINITY, m1 = -INFINITY, m2 = -INFINITY, m3 = -INFINITY;
  const int nc8 = ncols >> 3;
  const uint4* sr8 = (const uint4*)sr;
  float4* lds4 = (float4*)lds;
  for (int j = t; j < nc8; j += 256){
    uint4 v = sr8[j];
    float4 a = make_float4(bf2f(v.x & 0xffffu), bf2f(v.x >> 16),
                           bf2f(v.y & 0xffffu), bf2f(v.y >> 16));
    float4 b = make_float4(bf2f(v.z & 0xffffu), bf2f(v.z >> 16),
                           bf2f(v.w & 0xffffu), bf2f(v.w >> 16));
    lds4[j*2]   = a;
    lds4[j*2+1] = b;
    m0 = fmaxf(m0, fmaxf(a.x, b.x)); m1 = fmaxf(m1, fmaxf(a.y, b.y));
    m2 = fmaxf(m2, fmaxf(a.z, b.z)); m3 = fmaxf(m3, fmaxf(a.w, b.w));
  }
  for (int j = (nc8 << 3) + t; j < ncols; j += 256){
    float v = bf2f((unsigned)sr[j]);
    lds[j] = v;
    m0 = fmaxf(m0, v);
  }
  sv[t] = fmaxf(fmaxf(m0, m1), fmaxf(m2, m3));
  __syncthreads();

  for (int k = 2; k <= 256; k <<= 1){
    for (int j = k >> 1; j > 0; j >>= 1){
      int p = t ^ j;
      float a = sv[t], b = sv[p];
      bool up = ((t & k) == 0);
      float keep = (t < p) ? (up ? fmaxf(a,b) : fminf(a,b))
                           : (up ? fminf(a,b) : fmaxf(a,b));
      __syncthreads();
      sv[t] = keep;
      __syncthreads();
    }
  }
  if (t == 0){ tau_s = sv[31]; cnt = 0; }
  __syncthreads();
  const float thr = tau_s - eps;

  float* cs = cand_s + ((size_t)row * nchunks_total + gchunk) * cap;
  int*   ci = cand_i + ((size_t)row * nchunks_total + gchunk) * cap;

  for (int j = t; j < ncols; j += 256){
    float v = lds[j];
    if (v >= thr){
      int pos = atomicAdd(&cnt, 1);
      if (pos < cap){ cs[pos] = v; ci[pos] = colbase + col0l + j; }
    }
  }
  __syncthreads();
  int n = cnt < cap ? cnt : cap;
  for (int j = n + t; j < cap; j += 256) ci[j] = -1;
}

// ---------- select: prune (tau-trick on approx) -> fp32 rescore -> sort ----------
__global__ __launch_bounds__(256) void select_softmax_gather_kernel(
    const float* __restrict__ cand_s, const int* __restrict__ cand_i,
    const float* __restrict__ p, const float* __restrict__ rn_bank,
    const float* __restrict__ pnorm, const float* __restrict__ bank,
    float* __restrict__ z, int ncap, int D, int topm, float invtemp, float eps)
{
  __shared__ float p_s[1024];
  __shared__ float vs[1024]; __shared__ int vi[1024];
  __shared__ float sv[256];
  __shared__ int   cidx[256];
  __shared__ float rv[256];
  __shared__ float tau_s;
  __shared__ int cnt;
  const int row = blockIdx.x, t = threadIdx.x;
  const int lane = t & 63, wid = t >> 6;

  const float4* pr = (const float4*)(p + (size_t)row * D);
  for (int i = t; i < (D >> 2); i += 256) ((float4*)p_s)[i] = pr[i];
  const float* cs = cand_s + (size_t)row * ncap;
  const int*  ci = cand_i + (size_t)row * ncap;
  for (int j = t; j < ncap; j += 256){
    int k = ci[j];
    vi[j] = k;
    vs[j] = (k >= 0) ? cs[j] : -INFINITY;
  }
  __syncthreads();

  float m = -INFINITY;
  for (int j = t; j < ncap; j += 256) m = fmaxf(m, vs[j]);
  sv[t] = m;
  __syncthreads();
  for (int k = 2; k <= 256; k <<= 1){
    for (int j = k >> 1; j > 0; j >>= 1){
      int pp = t ^ j;
      float a = sv[t], b = sv[pp];
      bool up = ((t & k) == 0);
      float keep = (t < pp) ? (up ? fmaxf(a,b) : fminf(a,b))
                            : (up ? fminf(a,b) : fmaxf(a,b));
      __syncthreads();
      sv[t] = keep;
      __syncthreads();
    }
  }
  if (t == 0){ tau_s = sv[31]; cnt = 0; }
  __syncthreads();
  const float thr = tau_s - eps;

  for (int j = t; j < ncap; j += 256){
    if (vi[j] >= 0 && vs[j] >= thr){
      int pos = atomicAdd(&cnt, 1);
      if (pos < 256) cidx[pos] = vi[j];
    }
  }
  __syncthreads();
  const int n2 = cnt < 256 ? cnt : 256;
  rv[t] = -INFINITY;
  if (t >= n2) cidx[t] = 0x7fffffff;
  __syncthreads();

  const int nj = D >> 8;
  for (int c = wid; c < n2; c += 4){
    int idx = cidx[c];
    const float4* kr = (const float4*)(bank + (size_t)idx * D);
    float ss = 0.f;
    for (int j = 0; j < nj; ++j){
      float4 kv = kr[lane + j*64];
      float4 pv = *(const float4*)&p_s[(lane + j*64) << 2];
      ss = fmaf(pv.x,kv.x, fmaf(pv.y,kv.y, fmaf(pv.z,kv.z, fmaf(pv.w,kv.w, ss))));
    }
    #pragma unroll
    for (int off = 32; off; off >>= 1) ss += __shfl_xor(ss, off);
    if (lane == 0) rv[c] = ss * rn_bank[idx];
  }
  __syncthreads();

  for (int k = 2; k <= 256; k <<= 1){
    for (int j = k >> 1; j > 0; j >>= 1){
      int pp = t ^ j;
      float av = rv[t];  int ai = cidx[t];
      float bv = rv[pp]; int bi = cidx[pp];
      bool up = ((t & k) == 0);
      bool agtb = (av > bv) || (av == bv && ai < bi);
      bool keepA = (t < pp) ? (up ? agtb : !agtb)
                            : (up ? !agtb : agtb);
      __syncthreads();
      if (keepA){ rv[t] = av; cidx[t] = ai; } else { rv[t] = bv; cidx[t] = bi; }
      __syncthreads();
    }
  }

  if (t == 0){
    float pn = pnorm[row] * invtemp;
    float mx = rv[0] * pn;
    float sum = 0.f;
    for (int i = 0; i < topm; ++i){
      float w = expf(rv[i]*pn - mx);
      sv[i] = w; sum += w;
    }
    float inv = 1.f / sum;
    for (int i = 0; i < topm; ++i) sv[i] *= inv;
  }
  __syncthreads();

  for (int d4 = t; d4 < (D >> 2); d4 += 256){
    float ax=0.f, ay=0.f, az=0.f, aw=0.f;
    for (int i = 0; i < topm; ++i){
      float a = sv[i];
      const float4 v = *(const float4*)(bank + (size_t)cidx[i]*D + (d4<<2));
      ax = fmaf(a, v.x, ax); ay = fmaf(a, v.y, ay);
      az = fmaf(a, v.z, az); aw = fmaf(a, v.w, aw);
    }
    *(float4*)(z + (size_t)row*D + (d4<<2)) = make_float4(ax,ay,az,aw);
  }
}

// ---------- LayerNorm ----------
__global__ __launch_bounds__(256) void layernorm_kernel(
    const float* __restrict__ ref, const float* __restrict__ gamma,
    const float* __restrict__ beta, float* __restrict__ out, int D, float eps)
{
  __shared__ float s1[4], s2[4];
  const int row = blockIdx.x, t = threadIdx.x;
  const float4* xr = (const float4*)(ref + (size_t)row*D);
  int nv = D >> 2;
  float sum = 0.f, ssq = 0.f;
  for (int i = t; i < nv; i += 256){
    float4 v = xr[i];
    sum += v.x+v.y+v.z+v.w;
    ssq = fmaf(v.x,v.x, fmaf(v.y,v.y, fmaf(v.z,v.z, fmaf(v.w,v.w, ssq))));
  }
  const int lane = t & 63, wid = t >> 6;
  #pragma unroll
  for (int off = 32; off; off >>= 1){ sum += __shfl_xor(sum, off); ssq += __shfl_xor(ssq, off); }
  if (lane == 0){ s1[wid] = sum; s2[wid] = ssq; }
  __syncthreads();
  sum = s1[0]+s1[1]+s1[2]+s1[3];
  ssq = s2[0]+s2[1]+s2[2]+s2[3];
  float mu  = sum / (float)D;
  float var = ssq / (float)D - mu*mu;
  float rs  = rsqrtf(var + eps);
  const float4* g4 = (const float4*)gamma;
  const float4* b4 = (const float4*)beta;
  float4* o4 = (float4*)(out + (size_t)row*D);
  for (int i = t; i < nv; i += 256){
    float4 v = xr[i], g = g4[i], bb = b4[i];
    float4 o;
    o.x = (v.x-mu)*rs*g.x + bb.x;
    o.y = (v.y-mu)*rs*g.y + bb.y;
    o.z = (v.z-mu)*rs*g.z + bb.z;
    o.w = (v.w-mu)*rs*g.w + bb.w;
    o4[i] = o;
  }
}

// ---------------------------------------------------------------------------
extern "C" void kernel_launch(void* const* d_in, const int* in_sizes, int n_in,
                              void* d_out, int out_size, void* d_ws, size_t ws_size,
                              hipStream_t stream)
{
  const float* q       = (const float*)d_in[0];
  const float* bank    = (const float*)d_in[1];
  const float* proj_w  = (const float*)d_in[2];
  const float* proj_b  = (const float*)d_in[3];
  const float* unify_w = (const float*)d_in[4];
  const float* unify_b = (const float*)d_in[5];
  const float* gamma   = (const float*)d_in[6];
  const float* beta    = (const float*)d_in[7];

  const int D = in_sizes[6];
  const int B = in_sizes[0] / D;
  const int N = in_sizes[1] / D;
  const int S = in_sizes[2] / (D * D);   // 2 for this problem
  const int R = S * B;                   // stacked rows (both scales)
  const int TOPM = 32;
  const int CAP  = 64;
  const int NC   = 12544;
  const float INVTEMP = 1.0f / 0.07f;
  const float EPS = 0.025f;              // >= 2x (bf16 compute 7e-3 + bf16 store 4e-3)

  const int NCH = (N + NC - 1) / NC;

  char* wsb = (char*)d_ws;
  size_t off = 0;
  auto take = [&](size_t bytes)->char*{ char* p = wsb + off; off += align256(bytes); return p; };
  float* rn_bank = (float*)take((size_t)N*4);
  float* pnorm   = (float*)take((size_t)R*4);
  float* p       = (float*)take((size_t)R*D*4);
  float* z       = (float*)take((size_t)R*D*4);
  float* ref     = (float*)take((size_t)B*D*4);
  float* cand_s  = (float*)take((size_t)R*NCH*CAP*4);
  int*   cand_i  = (int*)  take((size_t)R*NCH*CAP*4);
  unsigned short* bank_bf = (unsigned short*)take((size_t)N*D*2);
  unsigned short* p_bf    = (unsigned short*)take((size_t)R*D*2);
  unsigned short* scores  = (unsigned short*)take((size_t)R*(size_t)N*2);

  // 1) fused bank norms + bf16(bank*rn)
  rnorm_convert_kernel<true><<<(N+3)/4, 256, 0, stream>>>(
      bank, rn_bank, bank_bf, N, D);

  // 2) p[s] = q @ proj_w[s]^T + proj_b[s]  (stacked: rows s*B..s*B+B)
  dim3 g1(D/64, B/64);
  for (int s = 0; s < S; ++s)
    gemm_nt_kernel<1,1,false><<<g1, 256, 0, stream>>>(
        q, proj_w + (size_t)s*D*D, proj_b + (size_t)s*D, nullptr,
        p + (size_t)s*B*D, B, D, D, D, D);

  // 3) fused stacked ||p|| norms + bf16 copy
  rnorm_convert_kernel<false><<<(R+3)/4, 256, 0, stream>>>(
      p, pnorm, p_bf, R, D);

  // 4) full-N scores (256^2 tile, 1D grid XCD-swizzled) + ONE tau-filter dispatch
  {
    int ntile = (N + 255) / 256;
    int nwg = (R / 256) * ntile;
    scores_mfma_kernel<<<nwg, 512, 0, stream>>>(
        p_bf, bank_bf, scores, R, N, D, N);
    chunk_filter_kernel<<<dim3(R, NCH), 256, (size_t)NC*4, stream>>>(
        scores, N, 0, N, NC, cand_s, cand_i,
        0, NCH, CAP, EPS);
  }

  // 5) prune + fp32 rescore + exact top-32 + softmax + gather (both scales)
  select_softmax_gather_kernel<<<R, 256, 0, stream>>>(
      cand_s, cand_i, p, rn_bank, pnorm, bank, z,
      NCH*CAP, D, TOPM, INVTEMP, EPS);

  // 6) ref = sum_s z[s] @ unify_w[s]^T + unify_b[s]
  for (int s = 0; s < S; ++s){
    if (s == 0)
      gemm_nt_kernel<1,1,false><<<g1, 256, 0, stream>>>(
          z + (size_t)s*B*D, unify_w + (size_t)s*D*D, unify_b + (size_t)s*D, nullptr,
          ref, B, D, D, D, D);
    else
      gemm_nt_kernel<1,1,true><<<g1, 256, 0, stream>>>(
          z + (size_t)s*B*D, unify_w + (size_t)s*D*D, unify_b + (size_t)s*D, nullptr,
          ref, B, D, D, D, D);
  }

  // 7) LayerNorm -> out
  layernorm_kernel<<<B, 256, 0, stream>>>(ref, gamma, beta, (float*)d_out, D, 1e-5f);
}

// Round 23
// 1385.161 us; speedup vs baseline: 1.0736x; 1.0736x over previous
//
#include <hip/hip_runtime.h>
#include <math.h>

// ---------------------------------------------------------------------------
// MultiScaleRetriever round 23:
// (a) scores kernel reverted to R19 exact config (128x128, BK=64, transposed
//     2D grid, no XCD swizzle) — best measured at 542us; R22's 256^2 regressed
//     (2 blocks/CU can't hide the single-buffer stage drain).
// (b) unify GEMMs fused: ref = [z0,z1] @ [W0;W1]^T + b0 + b1 as ONE K=2048
//     GEMM (wcat packed once, select writes zcat layout, dual-bias epilogue).
// ---------------------------------------------------------------------------

static inline size_t align256(size_t x){ return (x + 255) & ~size_t(255); }

typedef short bf16x8 __attribute__((ext_vector_type(8)));
typedef float f32x4  __attribute__((ext_vector_type(4)));

#define GLOAD_LDS16(gp, lp) \
  __builtin_amdgcn_global_load_lds((const __attribute__((address_space(1))) unsigned int*)(gp), \
                                   (__attribute__((address_space(3))) unsigned int*)(lp), 16, 0, 0)

__device__ inline unsigned short f2bf(float f){
  unsigned int u = __float_as_uint(f);
  u += 0x7fffu + ((u >> 16) & 1u);
  return (unsigned short)(u >> 16);
}
__device__ inline float bf2f(unsigned int h16){
  return __uint_as_float(h16 << 16);
}

// ---------- fused: row 1/max(||x||,eps) + bf16 convert (optional row scale) ----------
template<bool SCALE_OUT>
__global__ __launch_bounds__(256) void rnorm_convert_kernel(
    const float* __restrict__ X, float* __restrict__ rn,
    unsigned short* __restrict__ out, int rows, int D)
{
  int wv = threadIdx.x >> 6, lane = threadIdx.x & 63;
  int r = blockIdx.x * 4 + wv;
  if (r >= rows) return;
  const float4* xr = (const float4*)(X + (size_t)r * D);
  int nv = D >> 2;
  float ss = 0.f;
  for (int i = lane; i < nv; i += 64){
    float4 v = xr[i];
    ss = fmaf(v.x,v.x, fmaf(v.y,v.y, fmaf(v.z,v.z, fmaf(v.w,v.w, ss))));
  }
  #pragma unroll
  for (int off = 32; off; off >>= 1) ss += __shfl_xor(ss, off);
  float rinv = 1.f / fmaxf(sqrtf(ss), 1e-12f);
  if (lane == 0) rn[r] = rinv;
  const float sc = SCALE_OUT ? rinv : 1.f;
  unsigned short* orow = out + (size_t)r * D;
  for (int i = lane; i < (D >> 3); i += 64){
    float4 v0 = xr[i*2], v1 = xr[i*2+1];
    v0.x*=sc; v0.y*=sc; v0.z*=sc; v0.w*=sc;
    v1.x*=sc; v1.y*=sc; v1.z*=sc; v1.w*=sc;
    uint4 w;
    w.x = (unsigned)f2bf(v0.x) | ((unsigned)f2bf(v0.y) << 16);
    w.y = (unsigned)f2bf(v0.z) | ((unsigned)f2bf(v0.w) << 16);
    w.z = (unsigned)f2bf(v1.x) | ((unsigned)f2bf(v1.y) << 16);
    w.w = (unsigned)f2bf(v1.z) | ((unsigned)f2bf(v1.w) << 16);
    *(uint4*)(orow + i*8) = w;
  }
}

// ---------- pack wcat[n][s*D+k] = unify_w[s][n][k]  (float4 gather) ----------
__global__ __launch_bounds__(256) void pack_wcat_kernel(
    const float* __restrict__ W, float* __restrict__ wcat, int D, int S)
{
  long total4 = (long)D * S * D / 4;
  long i = (long)blockIdx.x * 256 + threadIdx.x;
  const long stride = (long)gridDim.x * 256;
  const int SD = S * D;
  for (; i < total4; i += stride){
    long e = i * 4;
    int n = (int)(e / SD);
    int c = (int)(e % SD);
    int s = c / D, k = c % D;
    float4 v = *(const float4*)(W + (size_t)s*D*D + (size_t)n*D + k);
    *(float4*)(wcat + e) = v;
  }
}

// ---------- fp32 NT GEMM (proj/unify): dual-bias epilogue ----------
template<int RM, int RN, bool ACCUM>
__global__ __launch_bounds__(256) void gemm_nt_kernel(
    const float* __restrict__ A, const float* __restrict__ B,
    const float* __restrict__ bias, const float* __restrict__ bias2,
    float* __restrict__ C, int M, int Nn, int K, int Brows, int ldc)
{
  __shared__ float As[16][RM*64 + 4];
  __shared__ float Bs[16][RN*64 + 4];
  const int t  = threadIdx.x;
  const int tm = t >> 4, tn = t & 15;
  const int m0 = blockIdx.y * (RM*64), n0 = blockIdx.x * (RN*64);

  float acc[RM][RN][4][4];
  #pragma unroll
  for (int r=0;r<RM;++r)
    #pragma unroll
    for (int c=0;c<RN;++c)
      #pragma unroll
      for (int i=0;i<4;++i)
        #pragma unroll
        for (int j=0;j<4;++j) acc[r][c][i][j]=0.f;

  for (int kp = 0; kp < K; kp += 16){
    #pragma unroll
    for (int l = 0; l < RM; ++l){
      int li = t + l*256;
      int row = li >> 2, kq = (li & 3) << 2;
      float4 v = *(const float4*)(A + (size_t)(m0+row)*K + kp + kq);
      As[kq+0][row]=v.x; As[kq+1][row]=v.y; As[kq+2][row]=v.z; As[kq+3][row]=v.w;
    }
    #pragma unroll
    for (int l = 0; l < RN; ++l){
      int li = t + l*256;
      int row = li >> 2, kq = (li & 3) << 2;
      int gn = n0 + row;
      float4 v = make_float4(0.f,0.f,0.f,0.f);
      if (gn < Brows)
        v = *(const float4*)(B + (size_t)gn*K + kp + kq);
      Bs[kq+0][row]=v.x; Bs[kq+1][row]=v.y; Bs[kq+2][row]=v.z; Bs[kq+3][row]=v.w;
    }
    __syncthreads();
    #pragma unroll
    for (int kk = 0; kk < 16; ++kk){
      float av[RM][4], bv[RN][4];
      #pragma unroll
      for (int r=0;r<RM;++r){
        float4 a = *(const float4*)&As[kk][r*64 + tm*4];
        av[r][0]=a.x; av[r][1]=a.y; av[r][2]=a.z; av[r][3]=a.w;
      }
      #pragma unroll
      for (int c=0;c<RN;++c){
        float4 b = *(const float4*)&Bs[kk][c*64 + tn*4];
        bv[c][0]=b.x; bv[c][1]=b.y; bv[c][2]=b.z; bv[c][3]=b.w;
      }
      #pragma unroll
      for (int r=0;r<RM;++r)
        #pragma unroll
        for (int c=0;c<RN;++c)
          #pragma unroll
          for (int i=0;i<4;++i)
            #pragma unroll
            for (int j=0;j<4;++j)
              acc[r][c][i][j] = fmaf(av[r][i], bv[c][j], acc[r][c][i][j]);
    }
    __syncthreads();
  }

  #pragma unroll
  for (int r=0;r<RM;++r){
    #pragma unroll
    for (int i=0;i<4;++i){
      int gm = m0 + r*64 + tm*4 + i;
      #pragma unroll
      for (int c=0;c<RN;++c){
        int gn = n0 + c*64 + tn*4;
        if (gn >= Nn) continue;
        float* cp = C + (size_t)gm*ldc + gn;
        float o0=acc[r][c][i][0], o1=acc[r][c][i][1], o2=acc[r][c][i][2], o3=acc[r][c][i][3];
        if (gn + 3 < Nn){
          float4 o = make_float4(o0,o1,o2,o3);
          if (bias){ float4 bb = *(const float4*)&bias[gn]; o.x+=bb.x; o.y+=bb.y; o.z+=bb.z; o.w+=bb.w; }
          if (bias2){ float4 bb = *(const float4*)&bias2[gn]; o.x+=bb.x; o.y+=bb.y; o.z+=bb.z; o.w+=bb.w; }
          if (ACCUM){ float4 cc = *(const float4*)cp; o.x+=cc.x; o.y+=cc.y; o.z+=cc.z; o.w+=cc.w; }
          *(float4*)cp = o;
        } else {
          float ov[4] = {o0,o1,o2,o3};
          for (int j=0;j<4;++j){
            if (gn + j < Nn){
              float o = ov[j];
              if (bias)  o += bias[gn+j];
              if (bias2) o += bias2[gn+j];
              if (ACCUM) o += cp[j];
              cp[j] = o;
            }
          }
        }
      }
    }
  }
}

// ---------- scores GEMM (R19 exact): 128x128, BK=64, transposed 2D grid ----------
__global__ __launch_bounds__(256) void scores_mfma_kernel(
    const unsigned short* __restrict__ Abf, const unsigned short* __restrict__ Bbf,
    unsigned short* __restrict__ C, int M, int Nn, int K, int ldc)
{
  __shared__ __align__(16) unsigned char smem[32768];   // A:[0,16K) B:[16K,32K)

  const int t = threadIdx.x;
  const int lane = t & 63, wid = t >> 6;
  const int wm = wid >> 1, wn = wid & 1;       // 2 x 2 wave grid
  const int l15 = lane & 15, l4 = lane >> 4;
  const int m0 = blockIdx.x * 128, n0 = blockIdx.y * 128;   // transposed

  f32x4 acc[4][4];
  #pragma unroll
  for (int i=0;i<4;++i)
    #pragma unroll
    for (int j=0;j<4;++j) acc[i][j] = (f32x4)0.f;

  const int srow = t >> 3;          // pass i adds 32
  const int sb   = (t & 7) * 16;
  const int ldsb = wid * 1024;      // wave-uniform base (+ lane*16 by HW)

  for (int kp = 0; kp < K; kp += 64){
    #pragma unroll
    for (int i = 0; i < 4; ++i){
      int row = srow + i*32;
      int src = sb ^ ((row & 7) << 4);
      const unsigned char* ga = (const unsigned char*)Abf
          + ((size_t)(m0+row)*K + kp)*2 + src;
      GLOAD_LDS16(ga, smem + i*4096 + ldsb);
      int gn = n0 + row; if (gn >= Nn) gn = Nn - 1;   // clamp: junk cols never read
      const unsigned char* gb = (const unsigned char*)Bbf
          + ((size_t)gn*K + kp)*2 + src;
      GLOAD_LDS16(gb, smem + 16384 + i*4096 + ldsb);
    }
    __syncthreads();

    const unsigned char* As_ = smem;
    const unsigned char* Bs_ = smem + 16384;
    bf16x8 B0[4], B1[4];
    #pragma unroll
    for (int fn = 0; fn < 4; ++fn){
      int br = wn*64 + fn*16 + l15;
      int xr = (br & 7) << 4;
      const unsigned char* bp = Bs_ + br*128;
      B0[fn] = *(const bf16x8*)(bp + (( l4*16      ) ^ xr));
      B1[fn] = *(const bf16x8*)(bp + ((64 + l4*16 ) ^ xr));
    }
    #pragma unroll
    for (int fm = 0; fm < 4; ++fm){
      int ar = wm*64 + fm*16 + l15;
      int xr = (ar & 7) << 4;
      const unsigned char* ap = As_ + ar*128;
      bf16x8 A0 = *(const bf16x8*)(ap + (( l4*16      ) ^ xr));
      bf16x8 A1 = *(const bf16x8*)(ap + ((64 + l4*16 ) ^ xr));
      #pragma unroll
      for (int fn = 0; fn < 4; ++fn){
        acc[fm][fn] = __builtin_amdgcn_mfma_f32_16x16x32_bf16(A0, B0[fn], acc[fm][fn], 0,0,0);
        acc[fm][fn] = __builtin_amdgcn_mfma_f32_16x16x32_bf16(A1, B1[fn], acc[fm][fn], 0,0,0);
      }
    }
    __syncthreads();
  }

  // store bf16 scores: C/D layout col=lane&15, row=(lane>>4)*4+reg
  #pragma unroll
  for (int fm = 0; fm < 4; ++fm){
    int row = m0 + wm*64 + fm*16 + l4*4;
    #pragma unroll
    for (int fn = 0; fn < 4; ++fn){
      int col = n0 + wn*64 + fn*16 + l15;
      if (col < Nn){
        unsigned short* cp = C + (size_t)row*ldc + col;
        #pragma unroll
        for (int r2 = 0; r2 < 4; ++r2) cp[(size_t)r2*ldc] = f2bf(acc[fm][fn][r2]);
      }
    }
  }
}

// ---------- chunk filter v3: bf16 scores in, f32 LDS cache, ILP max ----------
__global__ __launch_bounds__(256) void chunk_filter_kernel(
    const unsigned short* __restrict__ scores, int ldc, int colbase, int Nwindow,
    int NC, float* __restrict__ cand_s, int* __restrict__ cand_i,
    int chunk0, int nchunks_total, int cap, float eps)
{
  extern __shared__ float lds[];          // NC floats
  __shared__ float sv[256];
  __shared__ float tau_s;
  __shared__ int cnt;
  const int row = blockIdx.x, t = threadIdx.x;
  const int lc = blockIdx.y;
  const int col0l = lc * NC;
  int ncols = Nwindow - col0l; if (ncols > NC) ncols = NC;
  const int gchunk = chunk0 + lc;
  const unsigned short* sr = scores + (size_t)row * ldc + col0l;

  float m0 = -INFINITY, m1 = -INFINITY, m2 = -INFINITY, m3 = -INFINITY;
  const int nc8 = ncols >> 3;
  const uint4* sr8 = (const uint4*)sr;
  float4* lds4 = (float4*)lds;
  for (int j = t; j < nc8; j += 256){
    uint4 v = sr8[j];
    float4 a = make_float4(bf2f(v.x & 0xffffu), bf2f(v.x >> 16),
                           bf2f(v.y & 0xffffu), bf2f(v.y >> 16));
    float4 b = make_float4(bf2f(v.z & 0xffffu), bf2f(v.z >> 16),
                           bf2f(v.w & 0xffffu), bf2f(v.w >> 16));
    lds4[j*2]   = a;
    lds4[j*2+1] = b;
    m0 = fmaxf(m0, fmaxf(a.x, b.x)); m1 = fmaxf(m1, fmaxf(a.y, b.y));
    m2 = fmaxf(m2, fmaxf(a.z, b.z)); m3 = fmaxf(m3, fmaxf(a.w, b.w));
  }
  for (int j = (nc8 << 3) + t; j < ncols; j += 256){
    float v = bf2f((unsigned)sr[j]);
    lds[j] = v;
    m0 = fmaxf(m0, v);
  }
  sv[t] = fmaxf(fmaxf(m0, m1), fmaxf(m2, m3));
  __syncthreads();

  for (int k = 2; k <= 256; k <<= 1){
    for (int j = k >> 1; j > 0; j >>= 1){
      int p = t ^ j;
      float a = sv[t], b = sv[p];
      bool up = ((t & k) == 0);
      float keep = (t < p) ? (up ? fmaxf(a,b) : fminf(a,b))
                           : (up ? fminf(a,b) : fmaxf(a,b));
      __syncthreads();
      sv[t] = keep;
      __syncthreads();
    }
  }
  if (t == 0){ tau_s = sv[31]; cnt = 0; }
  __syncthreads();
  const float thr = tau_s - eps;

  float* cs = cand_s + ((size_t)row * nchunks_total + gchunk) * cap;
  int*   ci = cand_i + ((size_t)row * nchunks_total + gchunk) * cap;

  for (int j = t; j < ncols; j += 256){
    float v = lds[j];
    if (v >= thr){
      int pos = atomicAdd(&cnt, 1);
      if (pos < cap){ cs[pos] = v; ci[pos] = colbase + col0l + j; }
    }
  }
  __syncthreads();
  int n = cnt < cap ? cnt : cap;
  for (int j = n + t; j < cap; j += 256) ci[j] = -1;
}

// ---------- select: prune -> fp32 rescore -> sort; writes zcat layout ----------
__global__ __launch_bounds__(256) void select_softmax_gather_kernel(
    const float* __restrict__ cand_s, const int* __restrict__ cand_i,
    const float* __restrict__ p, const float* __restrict__ rn_bank,
    const float* __restrict__ pnorm, const float* __restrict__ bank,
    float* __restrict__ zcat, int srows, int ncap, int D, int topm,
    float invtemp, float eps)
{
  __shared__ float p_s[1024];
  __shared__ float vs[1024]; __shared__ int vi[1024];
  __shared__ float sv[256];
  __shared__ int   cidx[256];
  __shared__ float rv[256];
  __shared__ float tau_s;
  __shared__ int cnt;
  const int row = blockIdx.x, t = threadIdx.x;
  const int lane = t & 63, wid = t >> 6;

  const float4* pr = (const float4*)(p + (size_t)row * D);
  for (int i = t; i < (D >> 2); i += 256) ((float4*)p_s)[i] = pr[i];
  const float* cs = cand_s + (size_t)row * ncap;
  const int*  ci = cand_i + (size_t)row * ncap;
  for (int j = t; j < ncap; j += 256){
    int k = ci[j];
    vi[j] = k;
    vs[j] = (k >= 0) ? cs[j] : -INFINITY;
  }
  __syncthreads();

  float m = -INFINITY;
  for (int j = t; j < ncap; j += 256) m = fmaxf(m, vs[j]);
  sv[t] = m;
  __syncthreads();
  for (int k = 2; k <= 256; k <<= 1){
    for (int j = k >> 1; j > 0; j >>= 1){
      int pp = t ^ j;
      float a = sv[t], b = sv[pp];
      bool up = ((t & k) == 0);
      float keep = (t < pp) ? (up ? fmaxf(a,b) : fminf(a,b))
                            : (up ? fminf(a,b) : fmaxf(a,b));
      __syncthreads();
      sv[t] = keep;
      __syncthreads();
    }
  }
  if (t == 0){ tau_s = sv[31]; cnt = 0; }
  __syncthreads();
  const float thr = tau_s - eps;

  for (int j = t; j < ncap; j += 256){
    if (vi[j] >= 0 && vs[j] >= thr){
      int pos = atomicAdd(&cnt, 1);
      if (pos < 256) cidx[pos] = vi[j];
    }
  }
  __syncthreads();
  const int n2 = cnt < 256 ? cnt : 256;
  rv[t] = -INFINITY;
  if (t >= n2) cidx[t] = 0x7fffffff;
  __syncthreads();

  const int nj = D >> 8;
  for (int c = wid; c < n2; c += 4){
    int idx = cidx[c];
    const float4* kr = (const float4*)(bank + (size_t)idx * D);
    float ss = 0.f;
    for (int j = 0; j < nj; ++j){
      float4 kv = kr[lane + j*64];
      float4 pv = *(const float4*)&p_s[(lane + j*64) << 2];
      ss = fmaf(pv.x,kv.x, fmaf(pv.y,kv.y, fmaf(pv.z,kv.z, fmaf(pv.w,kv.w, ss))));
    }
    #pragma unroll
    for (int off = 32; off; off >>= 1) ss += __shfl_xor(ss, off);
    if (lane == 0) rv[c] = ss * rn_bank[idx];
  }
  __syncthreads();

  for (int k = 2; k <= 256; k <<= 1){
    for (int j = k >> 1; j > 0; j >>= 1){
      int pp = t ^ j;
      float av = rv[t];  int ai = cidx[t];
      float bv = rv[pp]; int bi = cidx[pp];
      bool up = ((t & k) == 0);
      bool agtb = (av > bv) || (av == bv && ai < bi);
      bool keepA = (t < pp) ? (up ? agtb : !agtb)
                            : (up ? !agtb : agtb);
      __syncthreads();
      if (keepA){ rv[t] = av; cidx[t] = ai; } else { rv[t] = bv; cidx[t] = bi; }
      __syncthreads();
    }
  }

  if (t == 0){
    float pn = pnorm[row] * invtemp;
    float mx = rv[0] * pn;
    float sum = 0.f;
    for (int i = 0; i < topm; ++i){
      float w = expf(rv[i]*pn - mx);
      sv[i] = w; sum += w;
    }
    float inv = 1.f / sum;
    for (int i = 0; i < topm; ++i) sv[i] *= inv;
  }
  __syncthreads();

  // write into zcat[b][s*D + d]  (row = s*srows + b)
  const int s = row / srows, b = row % srows;
  float* zr = zcat + (size_t)b * (2ull * D) * 0 /*placeholder*/;
  // compute properly: stride = S*D; here S derives from gridDim = S*srows
  const int S = gridDim.x / srows;
  zr = zcat + (size_t)b * ((size_t)S * D) + (size_t)s * D;
  for (int d4 = t; d4 < (D >> 2); d4 += 256){
    float ax=0.f, ay=0.f, az=0.f, aw=0.f;
    for (int i = 0; i < topm; ++i){
      float a = sv[i];
      const float4 v = *(const float4*)(bank + (size_t)cidx[i]*D + (d4<<2));
      ax = fmaf(a, v.x, ax); ay = fmaf(a, v.y, ay);
      az = fmaf(a, v.z, az); aw = fmaf(a, v.w, aw);
    }
    *(float4*)(zr + (d4<<2)) = make_float4(ax,ay,az,aw);
  }
}

// ---------- LayerNorm ----------
__global__ __launch_bounds__(256) void layernorm_kernel(
    const float* __restrict__ ref, const float* __restrict__ gamma,
    const float* __restrict__ beta, float* __restrict__ out, int D, float eps)
{
  __shared__ float s1[4], s2[4];
  const int row = blockIdx.x, t = threadIdx.x;
  const float4* xr = (const float4*)(ref + (size_t)row*D);
  int nv = D >> 2;
  float sum = 0.f, ssq = 0.f;
  for (int i = t; i < nv; i += 256){
    float4 v = xr[i];
    sum += v.x+v.y+v.z+v.w;
    ssq = fmaf(v.x,v.x, fmaf(v.y,v.y, fmaf(v.z,v.z, fmaf(v.w,v.w, ssq))));
  }
  const int lane = t & 63, wid = t >> 6;
  #pragma unroll
  for (int off = 32; off; off >>= 1){ sum += __shfl_xor(sum, off); ssq += __shfl_xor(ssq, off); }
  if (lane == 0){ s1[wid] = sum; s2[wid] = ssq; }
  __syncthreads();
  sum = s1[0]+s1[1]+s1[2]+s1[3];
  ssq = s2[0]+s2[1]+s2[2]+s2[3];
  float mu  = sum / (float)D;
  float var = ssq / (float)D - mu*mu;
  float rs  = rsqrtf(var + eps);
  const float4* g4 = (const float4*)gamma;
  const float4* b4 = (const float4*)beta;
  float4* o4 = (float4*)(out + (size_t)row*D);
  for (int i = t; i < nv; i += 256){
    float4 v = xr[i], g = g4[i], bb = b4[i];
    float4 o;
    o.x = (v.x-mu)*rs*g.x + bb.x;
    o.y = (v.y-mu)*rs*g.y + bb.y;
    o.z = (v.z-mu)*rs*g.z + bb.z;
    o.w = (v.w-mu)*rs*g.w + bb.w;
    o4[i] = o;
  }
}

// ---------------------------------------------------------------------------
extern "C" void kernel_launch(void* const* d_in, const int* in_sizes, int n_in,
                              void* d_out, int out_size, void* d_ws, size_t ws_size,
                              hipStream_t stream)
{
  const float* q       = (const float*)d_in[0];
  const float* bank    = (const float*)d_in[1];
  const float* proj_w  = (const float*)d_in[2];
  const float* proj_b  = (const float*)d_in[3];
  const float* unify_w = (const float*)d_in[4];
  const float* unify_b = (const float*)d_in[5];
  const float* gamma   = (const float*)d_in[6];
  const float* beta    = (const float*)d_in[7];

  const int D = in_sizes[6];
  const int B = in_sizes[0] / D;
  const int N = in_sizes[1] / D;
  const int S = in_sizes[2] / (D * D);   // 2 for this problem
  const int R = S * B;                   // stacked rows (both scales)
  const int SD = S * D;
  const int TOPM = 32;
  const int CAP  = 64;
  const int NC   = 12544;
  const float INVTEMP = 1.0f / 0.07f;
  const float EPS = 0.025f;              // >= 2x (bf16 compute 7e-3 + bf16 store 4e-3)

  const int NCH = (N + NC - 1) / NC;

  char* wsb = (char*)d_ws;
  size_t off = 0;
  auto take = [&](size_t bytes)->char*{ char* p = wsb + off; off += align256(bytes); return p; };
  float* rn_bank = (float*)take((size_t)N*4);
  float* pnorm   = (float*)take((size_t)R*4);
  float* p       = (float*)take((size_t)R*D*4);
  float* zcat    = (float*)take((size_t)B*SD*4);
  float* wcat    = (float*)take((size_t)D*SD*4);
  float* ref     = (float*)take((size_t)B*D*4);
  float* cand_s  = (float*)take((size_t)R*NCH*CAP*4);
  int*   cand_i  = (int*)  take((size_t)R*NCH*CAP*4);
  unsigned short* bank_bf = (unsigned short*)take((size_t)N*D*2);
  unsigned short* p_bf    = (unsigned short*)take((size_t)R*D*2);
  unsigned short* scores  = (unsigned short*)take((size_t)R*(size_t)N*2);

  // 1) fused bank norms + bf16(bank*rn); pack wcat for fused unify
  rnorm_convert_kernel<true><<<(N+3)/4, 256, 0, stream>>>(
      bank, rn_bank, bank_bf, N, D);
  pack_wcat_kernel<<<512, 256, 0, stream>>>(unify_w, wcat, D, S);

  // 2) p[s] = q @ proj_w[s]^T + proj_b[s]  (stacked: rows s*B..s*B+B)
  dim3 g1(D/64, B/64);
  for (int s = 0; s < S; ++s)
    gemm_nt_kernel<1,1,false><<<g1, 256, 0, stream>>>(
        q, proj_w + (size_t)s*D*D, proj_b + (size_t)s*D, nullptr,
        p + (size_t)s*B*D, B, D, D, D, D);

  // 3) fused stacked ||p|| norms + bf16 copy
  rnorm_convert_kernel<false><<<(R+3)/4, 256, 0, stream>>>(
      p, pnorm, p_bf, R, D);

  // 4) full-N scores (R19 config) + ONE tau-filter dispatch
  {
    dim3 g2(R/128, (N + 127)/128);          // x = M-tiles (fast), y = N-tiles
    scores_mfma_kernel<<<g2, 256, 0, stream>>>(
        p_bf, bank_bf, scores, R, N, D, N);
    chunk_filter_kernel<<<dim3(R, NCH), 256, (size_t)NC*4, stream>>>(
        scores, N, 0, N, NC, cand_s, cand_i,
        0, NCH, CAP, EPS);
  }

  // 5) prune + fp32 rescore + exact top-32 + softmax + gather -> zcat
  select_softmax_gather_kernel<<<R, 256, 0, stream>>>(
      cand_s, cand_i, p, rn_bank, pnorm, bank, zcat, B,
      NCH*CAP, D, TOPM, INVTEMP, EPS);

  // 6) ref = zcat @ wcat^T + b0 + b1   (single fused K=S*D GEMM)
  gemm_nt_kernel<1,1,false><<<g1, 256, 0, stream>>>(
      zcat, wcat, unify_b, unify_b + D,
      ref, B, D, SD, D, D);

  // 7) LayerNorm -> out
  layernorm_kernel<<<B, 256, 0, stream>>>(ref, gamma, beta, (float*)d_out, D, 1e-5f);
}